// Round 6
// baseline (213.988 us; speedup 1.0000x reference)
//
#include <hip/hip_runtime.h>

#define T_LEN 2048
#define DIM 2048
#define NH 16
#define HD 128
#define QKV_LD 6144   // 3*DIM

typedef __attribute__((ext_vector_type(8))) short short8;
typedef __attribute__((ext_vector_type(4))) float f32x4;
typedef __attribute__((ext_vector_type(4))) float float4v;
typedef __attribute__((ext_vector_type(4))) unsigned short ushort4v;
typedef __attribute__((ext_vector_type(2))) unsigned int uint2v;

static __device__ __forceinline__ unsigned short f2bf(float f) {
  unsigned u = __builtin_bit_cast(unsigned, f);
  u += 0x7fffu + ((u >> 16) & 1u);   // round-to-nearest-even
  return (unsigned short)(u >> 16);
}

static __device__ __forceinline__ float bf2f(unsigned short u) {
  unsigned x = ((unsigned)u) << 16;
  return __builtin_bit_cast(float, x);
}

static __device__ __forceinline__ float max3f(float a, float b, float c) {
  return fmaxf(fmaxf(a, b), c);      // clang fuses to v_max3_f32
}

static __device__ __forceinline__ f32x4 mfma16(short8 a, short8 b, f32x4 c) {
  return __builtin_amdgcn_mfma_f32_16x16x32_bf16(a, b, c, 0, 0, 0);
}

#define GLDS16(SRC, DST)                                                            \
  __builtin_amdgcn_global_load_lds((__attribute__((address_space(1))) void*)(SRC),  \
                                   (__attribute__((address_space(3))) void*)(DST),  \
                                   16, 0, 0)

// ---------------------------------------------------------------- cast fp32->bf16
__global__ void cast_f32_bf16(const float* __restrict__ in,
                              unsigned short* __restrict__ out, int n4) {
  int i = blockIdx.x * blockDim.x + threadIdx.x;
  const int stride = gridDim.x * blockDim.x;
  for (; i < n4; i += stride) {
    float4v f = ((const float4v*)in)[i];
    ushort4v o;
    o.x = f2bf(f.x); o.y = f2bf(f.y); o.z = f2bf(f.z); o.w = f2bf(f.w);
    ((ushort4v*)out)[i] = o;
  }
}

// ---------------------------------------------------------------- GEMM: C = A * B^T
template <int OUT_BF16>
__global__ __launch_bounds__(256) void gemm_bt_128(
    const unsigned short* __restrict__ A,
    const unsigned short* __restrict__ B,
    void* __restrict__ Cv, int M, int N, int K) {
  __shared__ unsigned short As[128 * 64];
  __shared__ unsigned short Bs[128 * 64];
  const int tid = threadIdx.x;
  const int wave = tid >> 6;
  const int lane = tid & 63;
  const int l15 = lane & 15, l16 = lane >> 4;
  const int bm = blockIdx.y * 128;
  const int bn = blockIdx.x * 128;
  const int wr = wave >> 1, wc = wave & 1;

  f32x4 acc[4][4] = {};

  int srow[4], scol[4];
#pragma unroll
  for (int i = 0; i < 4; ++i) {
    int lin = i * 4096 + tid * 16;
    int row = lin >> 7;
    int cb = lin & 127;
    srow[i] = row;
    scol[i] = (cb ^ ((row & 7) << 4)) >> 1;
  }

  for (int k0 = 0; k0 < K; k0 += 64) {
#pragma unroll
    for (int i = 0; i < 4; ++i) {
      GLDS16(A + (size_t)(bm + srow[i]) * K + k0 + scol[i], As + i * 2048 + wave * 512);
      GLDS16(B + (size_t)(bn + srow[i]) * K + k0 + scol[i], Bs + i * 2048 + wave * 512);
    }
    __syncthreads();
#pragma unroll
    for (int kk = 0; kk < 2; ++kk) {
      const int cb = kk * 64 + l16 * 16;
      short8 af[4], bfr[4];
#pragma unroll
      for (int m = 0; m < 4; ++m) {
        int row = wr * 64 + m * 16 + l15;
        af[m] = *(const short8*)((const char*)As + row * 128 + (cb ^ ((row & 7) << 4)));
      }
#pragma unroll
      for (int n = 0; n < 4; ++n) {
        int row = wc * 64 + n * 16 + l15;
        bfr[n] = *(const short8*)((const char*)Bs + row * 128 + (cb ^ ((row & 7) << 4)));
      }
#pragma unroll
      for (int m = 0; m < 4; ++m)
#pragma unroll
        for (int n = 0; n < 4; ++n)
          acc[m][n] = mfma16(af[m], bfr[n], acc[m][n]);
    }
    __syncthreads();
  }

#pragma unroll
  for (int m = 0; m < 4; ++m)
#pragma unroll
    for (int n = 0; n < 4; ++n) {
      int row = bm + wr * 64 + m * 16 + l16 * 4;
      int col = bn + wc * 64 + n * 16 + l15;
#pragma unroll
      for (int j = 0; j < 4; ++j) {
        if (OUT_BF16)
          ((unsigned short*)Cv)[(size_t)(row + j) * N + col] = f2bf(acc[m][n][j]);
        else
          ((float*)Cv)[(size_t)(row + j) * N + col] = acc[m][n][j];
      }
    }
}

// ---------------------------------------------------------------- V transpose
__global__ __launch_bounds__(256) void transpose_v(
    const unsigned short* __restrict__ qkv, unsigned short* __restrict__ vt) {
  __shared__ unsigned short t[64 * 128];
  const int tid = threadIdx.x;
  const int h = blockIdx.y;
  const int s0 = blockIdx.x * 64;
#pragma unroll
  for (int i = 0; i < 4; ++i) {
    int lin = i * 2048 + tid * 8;
    int row = lin >> 7, col = lin & 127;
    char* dst = (char*)t + row * 256 + ((col * 2) ^ (((row >> 3) & 7) << 4));
    *(short8*)dst =
        *(const short8*)(qkv + (size_t)(s0 + row) * QKV_LD + 2 * DIM + h * HD + col);
  }
  __syncthreads();
#pragma unroll
  for (int i2 = 0; i2 < 4; ++i2) {
    int d = (tid >> 3) + i2 * 32;
    int sb = (tid & 7) * 8;
    short8 v;
#pragma unroll
    for (int j = 0; j < 8; ++j) {
      int s = sb + j;
      v[j] = *(const short*)((const char*)t + s * 256 + ((d * 2) ^ (((s >> 3) & 7) << 4)));
    }
    *(short8*)(vt + ((size_t)h * HD + d) * T_LEN + s0 + sb) = v;
  }
}

// ---------------------------------------------------------------- flash attention
// QBLK=32 per wave (halves LDS-read bytes per FLOP — the R5-diagnosed per-CU
// DS-bandwidth ceiling). 4 waves x 32q = 128 q/block; split-KV x2 keeps 512
// blocks = 2/CU. K double-buffered via global_load_lds DMA; V reg-staged
// (T14: global->VGPR at tile top, swizzled ds_write after post-PV barrier);
// P per-wave in LDS. Swapped QK^T, lane-local softmax, defer-max, setprio.
// LDS = 32K (K dbuf) + 16K (V) + 16K (P) = 64KB -> 2 blocks/CU.
__global__ __launch_bounds__(256) void attn_fwd(
    const unsigned short* __restrict__ qkv,
    const unsigned short* __restrict__ vt,
    unsigned short* __restrict__ po,    // [2][NH*T_LEN][HD] bf16 partial O
    float* __restrict__ ml) {           // [2][NH*T_LEN][2] f32 (m, l)
  __shared__ unsigned short Ks[2][64 * 128];
  __shared__ unsigned short Vs[128 * 64];
  __shared__ unsigned short Ps[4 * 32 * 64];
  const int tid = threadIdx.x;
  const int wave = tid >> 6;
  const int lane = tid & 63;
  const int l15 = lane & 15, l16 = lane >> 4;

  // XCD swizzle: 512 wgs, XCD x gets swz in [x*64, x*64+64) = heads {2x,2x+1}
  // (both halves, all q-blocks): per-XCD K/V set 2MB < 4MB L2.
  const int wg = blockIdx.y * 32 + blockIdx.x;
  const int swz = (wg & 7) * 64 + (wg >> 3);
  const int h = swz >> 5;
  const int khalf = (swz >> 4) & 1;
  const int q0 = (swz & 15) * 128 + wave * 32;
  const int s_begin = khalf * (T_LEN / 2);
  const float SCL = 0.08838834764831845f * 1.4426950408889634f;  // 1/sqrt(128)*log2(e)

  // Q fragments: Q[q0 + qh*16 + l15][kk*32 + l16*8 .. +7]
  short8 qf[2][4];
#pragma unroll
  for (int qh = 0; qh < 2; ++qh)
#pragma unroll
    for (int kk = 0; kk < 4; ++kk)
      qf[qh][kk] = *(const short8*)(qkv + (size_t)(q0 + qh * 16 + l15) * QKV_LD +
                                    h * HD + kk * 32 + l16 * 8);

  f32x4 acc0[8] = {}, acc1[8] = {};
  float m_r0 = -1e30f, m_r1 = -1e30f;   // running max (log2 domain), q = qh*16+l15
  float l_r0 = 0.f, l_r1 = 0.f;

  // K DMA source pointers (inverse-swizzled), bumped per tile
  const unsigned short* kp[4];
#pragma unroll
  for (int i = 0; i < 4; ++i) {
    int lin = i * 4096 + tid * 16;
    int r = lin >> 8;                       // K tile: 256B rows
    int cb = lin & 255;
    kp[i] = qkv + 2048 + h * HD + (size_t)(s_begin + r) * QKV_LD +
            ((cb ^ ((r & 7) << 4)) >> 1);
  }
  // V reg-stage: global pointers (linear) + swizzled LDS write offsets
  const unsigned short* vp[4];
  int woff[4];
#pragma unroll
  for (int i = 0; i < 4; ++i) {
    int d = wave * 32 + i * 8 + (lane >> 3);
    vp[i] = vt + (size_t)h * HD * T_LEN + (size_t)d * T_LEN + s_begin + (lane & 7) * 8;
    woff[i] = d * 128 + (((lane & 7) * 16) ^ ((d & 7) << 4));
  }

  // prologue: stage tile 0 (K via DMA, V via regs->LDS)
  short8 vreg[4];
#pragma unroll
  for (int i = 0; i < 4; ++i) {
    vreg[i] = *(const short8*)vp[i];
    vp[i] += 64;
  }
#pragma unroll
  for (int i = 0; i < 4; ++i) {
    GLDS16(kp[i], Ks[0] + i * 2048 + wave * 512);
    kp[i] += 64 * QKV_LD;
  }
#pragma unroll
  for (int i = 0; i < 4; ++i) *(short8*)((char*)Vs + woff[i]) = vreg[i];
  __syncthreads();

  const int NT = (T_LEN / 2) / 64;   // 16 tiles per half
  int cur = 0;
  for (int t = 0; t < NT; ++t) {
    // prefetch tile t+1: K -> other LDS buffer (DMA), V -> registers
    if (t + 1 < NT) {
#pragma unroll
      for (int i = 0; i < 4; ++i) {
        GLDS16(kp[i], Ks[cur ^ 1] + i * 2048 + wave * 512);
        kp[i] += 64 * QKV_LD;
      }
#pragma unroll
      for (int i = 0; i < 4; ++i) {
        vreg[i] = *(const short8*)vp[i];
        vp[i] += 64;
      }
    }
    const unsigned short* ks = Ks[cur];

    // S^T = K Q^T : lane holds S[kv = c*16 + l16*4 + j][q = qh*16 + l15]
    f32x4 st0[4] = {}, st1[4] = {};
    __builtin_amdgcn_s_setprio(1);
#pragma unroll
    for (int c = 0; c < 4; ++c) {
#pragma unroll
      for (int kk = 0; kk < 4; ++kk) {
        int row = c * 16 + l15;
        int cb = kk * 64 + l16 * 16;
        short8 kf = *(const short8*)((const char*)ks + row * 256 + (cb ^ ((row & 7) << 4)));
        st0[c] = mfma16(kf, qf[0][kk], st0[c]);
        st1[c] = mfma16(kf, qf[1][kk], st1[c]);
      }
    }
    __builtin_amdgcn_s_setprio(0);

    // ---- online softmax (per qh), lane-local for q-row l15 ----
    float ma0 = max3f(st0[0][0], st0[0][1], st0[0][2]);
    float mb0 = max3f(st0[0][3], st0[1][0], st0[1][1]);
    float mc0 = max3f(st0[1][2], st0[1][3], st0[2][0]);
    float md0 = max3f(st0[2][1], st0[2][2], st0[2][3]);
    float me0 = max3f(st0[3][0], st0[3][1], st0[3][2]);
    float pmax0 = fmaxf(max3f(ma0, mb0, mc0), max3f(md0, me0, st0[3][3])) * SCL;
    float ma1 = max3f(st1[0][0], st1[0][1], st1[0][2]);
    float mb1 = max3f(st1[0][3], st1[1][0], st1[1][1]);
    float mc1 = max3f(st1[1][2], st1[1][3], st1[2][0]);
    float md1 = max3f(st1[2][1], st1[2][2], st1[2][3]);
    float me1 = max3f(st1[3][0], st1[3][1], st1[3][2]);
    float pmax1 = fmaxf(max3f(ma1, mb1, mc1), max3f(md1, me1, st1[3][3])) * SCL;
    pmax0 = fmaxf(pmax0, __shfl_xor(pmax0, 16));
    pmax0 = fmaxf(pmax0, __shfl_xor(pmax0, 32));
    pmax1 = fmaxf(pmax1, __shfl_xor(pmax1, 16));
    pmax1 = fmaxf(pmax1, __shfl_xor(pmax1, 32));

    // defer-max: rescale only when a tile max exceeds running max by >8 (log2)
    float need = fmaxf(pmax0 - m_r0, pmax1 - m_r1);
    if (!__all(need <= 8.0f)) {
      float nm0 = fmaxf(m_r0, pmax0);
      float corr0 = __builtin_amdgcn_exp2f(m_r0 - nm0);
      m_r0 = nm0; l_r0 *= corr0;
      float nm1 = fmaxf(m_r1, pmax1);
      float corr1 = __builtin_amdgcn_exp2f(m_r1 - nm1);
      m_r1 = nm1; l_r1 *= corr1;
      float cj0[4], cj1[4];
#pragma unroll
      for (int j = 0; j < 4; ++j) {
        cj0[j] = __shfl(corr0, l16 * 4 + j);
        cj1[j] = __shfl(corr1, l16 * 4 + j);
      }
#pragma unroll
      for (int d = 0; d < 8; ++d)
#pragma unroll
        for (int j = 0; j < 4; ++j) {
          acc0[d][j] *= cj0[j];
          acc1[d][j] *= cj1[j];
        }
    }

    float p0[4][4], p1[4][4];
#pragma unroll
    for (int c = 0; c < 4; ++c)
#pragma unroll
      for (int j = 0; j < 4; ++j) {
        p0[c][j] = __builtin_amdgcn_exp2f(st0[c][j] * SCL - m_r0);
        p1[c][j] = __builtin_amdgcn_exp2f(st1[c][j] * SCL - m_r1);
      }
    float ts0 = ((p0[0][0] + p0[0][1]) + (p0[0][2] + p0[0][3])) +
                ((p0[1][0] + p0[1][1]) + (p0[1][2] + p0[1][3])) +
                (((p0[2][0] + p0[2][1]) + (p0[2][2] + p0[2][3])) +
                 ((p0[3][0] + p0[3][1]) + (p0[3][2] + p0[3][3])));
    float ts1 = ((p1[0][0] + p1[0][1]) + (p1[0][2] + p1[0][3])) +
                ((p1[1][0] + p1[1][1]) + (p1[1][2] + p1[1][3])) +
                (((p1[2][0] + p1[2][1]) + (p1[2][2] + p1[2][3])) +
                 ((p1[3][0] + p1[3][1]) + (p1[3][2] + p1[3][3])));
    ts0 += __shfl_xor(ts0, 16);
    ts0 += __shfl_xor(ts0, 32);
    ts1 += __shfl_xor(ts1, 16);
    ts1 += __shfl_xor(ts1, 32);
    l_r0 += ts0;
    l_r1 += ts1;

    // ---- P -> LDS: pack bf16 pairs, 8x ds_write_b64, swizzled rows 128B ----
    char* pbase = (char*)Ps + wave * 4096;
#pragma unroll
    for (int c = 0; c < 4; ++c) {
      uint2v w0, w1;
      w0.x = (unsigned)f2bf(p0[c][0]) | ((unsigned)f2bf(p0[c][1]) << 16);
      w0.y = (unsigned)f2bf(p0[c][2]) | ((unsigned)f2bf(p0[c][3]) << 16);
      w1.x = (unsigned)f2bf(p1[c][0]) | ((unsigned)f2bf(p1[c][1]) << 16);
      w1.y = (unsigned)f2bf(p1[c][2]) | ((unsigned)f2bf(p1[c][3]) << 16);
      int off0 = l15 * 128 + c * 32 + l16 * 8;
      int off1 = (16 + l15) * 128 + c * 32 + l16 * 8;
      *(uint2v*)(pbase + (off0 ^ ((l15 & 7) << 4))) = w0;
      *(uint2v*)(pbase + (off1 ^ ((l15 & 7) << 4))) = w1;
    }

    // ---- acc += P @ V  (V fragments reused across both qh groups) ----
    __builtin_amdgcn_s_setprio(1);
#pragma unroll
    for (int kk = 0; kk < 2; ++kk) {
      int cb = kk * 64 + l16 * 16;
      short8 pa0 = *(const short8*)(pbase + ((l15 * 128 + cb) ^ ((l15 & 7) << 4)));
      short8 pa1 = *(const short8*)(pbase + (((16 + l15) * 128 + cb) ^ ((l15 & 7) << 4)));
#pragma unroll
      for (int d = 0; d < 8; ++d) {
        int row = d * 16 + l15;
        short8 vb = *(const short8*)((const char*)Vs + row * 128 + (cb ^ ((row & 7) << 4)));
        acc0[d] = mfma16(pa0, vb, acc0[d]);
        acc1[d] = mfma16(pa1, vb, acc1[d]);
      }
    }
    __builtin_amdgcn_s_setprio(0);

    __syncthreads();   // all waves done with Vs/K[cur]; prefetches drained
    if (t + 1 < NT) {
#pragma unroll
      for (int i = 0; i < 4; ++i) *(short8*)((char*)Vs + woff[i]) = vreg[i];
    }
    __syncthreads();   // Vs(t+1) visible
    cur ^= 1;
  }

  // epilogue: write UNNORMALIZED partials. po[khalf][h*T+q][d], ml = (m, l)
  const size_t pb = ((size_t)khalf * NH * T_LEN + (size_t)h * T_LEN) * HD;
#pragma unroll
  for (int d = 0; d < 8; ++d)
#pragma unroll
    for (int j = 0; j < 4; ++j) {
      int qa = q0 + l16 * 4 + j;
      int qb = q0 + 16 + l16 * 4 + j;
      po[pb + (size_t)qa * HD + d * 16 + l15] = f2bf(acc0[d][j]);
      po[pb + (size_t)qb * HD + d * 16 + l15] = f2bf(acc1[d][j]);
    }
  if (l16 == 0) {
    size_t b0 = ((size_t)khalf * NH * T_LEN + (size_t)h * T_LEN + q0 + l15) * 2;
    size_t b1 = ((size_t)khalf * NH * T_LEN + (size_t)h * T_LEN + q0 + 16 + l15) * 2;
    ml[b0] = m_r0; ml[b0 + 1] = l_r0;
    ml[b1] = m_r1; ml[b1 + 1] = l_r1;
  }
}

// ---------------------------------------------------------------- combine halves
__global__ __launch_bounds__(256) void attn_combine(
    const unsigned short* __restrict__ po, const float* __restrict__ ml,
    unsigned short* __restrict__ ctx) {
  const int g = blockIdx.x * 256 + threadIdx.x;   // 524288 total
  const int hq = g >> 4;          // h*T_LEN + q  in [0, 32768)
  const int oct = g & 15;         // d-octet
  const float m0 = ml[hq * 2], l0 = ml[hq * 2 + 1];
  const float m1 = ml[NH * T_LEN * 2 + hq * 2], l1 = ml[NH * T_LEN * 2 + hq * 2 + 1];
  const float m = fmaxf(m0, m1);
  float a0 = __builtin_amdgcn_exp2f(m0 - m);
  float a1 = __builtin_amdgcn_exp2f(m1 - m);
  const float rl = 1.0f / (l0 * a0 + l1 * a1);
  a0 *= rl; a1 *= rl;
  const short8 o0 = *(const short8*)(po + (size_t)hq * HD + oct * 8);
  const short8 o1 = *(const short8*)(po + (size_t)NH * T_LEN * HD + (size_t)hq * HD + oct * 8);
  short8 w;
#pragma unroll
  for (int j = 0; j < 8; ++j)
    w[j] = (short)f2bf(bf2f((unsigned short)o0[j]) * a0 + bf2f((unsigned short)o1[j]) * a1);
  const int h = hq >> 11, q = hq & (T_LEN - 1);
  *(short8*)(ctx + (size_t)q * DIM + h * HD + oct * 8) = w;
}

// ---------------------------------------------------------------- launcher
extern "C" void kernel_launch(void* const* d_in, const int* in_sizes, int n_in,
                              void* d_out, int out_size, void* d_ws, size_t ws_size,
                              hipStream_t stream) {
  const float* x = (const float*)d_in[0];
  const float* w_in = (const float*)d_in[1];
  const float* w_out = (const float*)d_in[2];

  char* ws = (char*)d_ws;
  unsigned short* xbf  = (unsigned short*)(ws + 0);          //  8 MB
  unsigned short* wibf = (unsigned short*)(ws + 8388608);    // 24 MB
  unsigned short* wobf = (unsigned short*)(ws + 33554432);   //  8 MB
  unsigned short* qkv  = (unsigned short*)(ws + 41943040);   // 24 MB
  unsigned short* ctx  = (unsigned short*)(ws + 67108864);   //  8 MB
  unsigned short* vt   = (unsigned short*)(ws + 75497472);   //  8 MB  (end: 80 MB)
  // attention partials REUSE the xbf+wibf region [0, 32MB) — dead after GEMM1:
  unsigned short* po   = (unsigned short*)(ws + 0);          // 16 MB (2 halves x 8MB)
  float*          ml   = (float*)(ws + 16777216);            // 512 KB

  cast_f32_bf16<<<2048, 256, 0, stream>>>(x, xbf, (T_LEN * DIM) / 4);
  cast_f32_bf16<<<2048, 256, 0, stream>>>(w_in, wibf, (3 * DIM * DIM) / 4);
  cast_f32_bf16<<<2048, 256, 0, stream>>>(w_out, wobf, (DIM * DIM) / 4);

  // qkv = x @ w_in^T   [2048 x 6144]
  gemm_bt_128<1><<<dim3(48, 16), 256, 0, stream>>>(xbf, wibf, (void*)qkv, T_LEN, 3 * DIM, DIM);
  // vt[h][d][s] = V
  transpose_v<<<dim3(32, 16), 256, 0, stream>>>(qkv, vt);
  // attention partials (split-KV, QBLK=32/wave), then combine -> ctx
  attn_fwd<<<dim3(32, 16), 256, 0, stream>>>(qkv, vt, po, ml);
  attn_combine<<<2048, 256, 0, stream>>>(po, ml, ctx);
  // out = ctx @ w_out^T  (fp32)
  gemm_bt_128<0><<<dim3(16, 16), 256, 0, stream>>>(ctx, wobf, d_out, T_LEN, DIM, DIM);
}

// Round 7
// 208.509 us; speedup vs baseline: 1.0263x; 1.0263x over previous
//
#include <hip/hip_runtime.h>

#define T_LEN 2048
#define DIM 2048
#define NH 16
#define HD 128
#define QKV_LD 6144   // 3*DIM

typedef __attribute__((ext_vector_type(8))) short short8;
typedef __attribute__((ext_vector_type(4))) float f32x4;
typedef __attribute__((ext_vector_type(4))) float float4v;
typedef __attribute__((ext_vector_type(4))) unsigned short ushort4v;
typedef __attribute__((ext_vector_type(2))) unsigned int uint2v;

static __device__ __forceinline__ unsigned short f2bf(float f) {
  unsigned u = __builtin_bit_cast(unsigned, f);
  u += 0x7fffu + ((u >> 16) & 1u);   // round-to-nearest-even
  return (unsigned short)(u >> 16);
}

static __device__ __forceinline__ float max3f(float a, float b, float c) {
  return fmaxf(fmaxf(a, b), c);      // clang fuses to v_max3_f32
}

static __device__ __forceinline__ f32x4 mfma16(short8 a, short8 b, f32x4 c) {
  return __builtin_amdgcn_mfma_f32_16x16x32_bf16(a, b, c, 0, 0, 0);
}

#define GLDS16(SRC, DST)                                                            \
  __builtin_amdgcn_global_load_lds((__attribute__((address_space(1))) void*)(SRC),  \
                                   (__attribute__((address_space(3))) void*)(DST),  \
                                   16, 0, 0)

// ---------------------------------------------------------------- cast fp32->bf16
__global__ void cast_f32_bf16(const float* __restrict__ in,
                              unsigned short* __restrict__ out, int n4) {
  int i = blockIdx.x * blockDim.x + threadIdx.x;
  const int stride = gridDim.x * blockDim.x;
  for (; i < n4; i += stride) {
    float4v f = ((const float4v*)in)[i];
    ushort4v o;
    o.x = f2bf(f.x); o.y = f2bf(f.y); o.z = f2bf(f.z); o.w = f2bf(f.w);
    ((ushort4v*)out)[i] = o;
  }
}

// ---------------------------------------------------------------- GEMM 256x256 8-phase
// C = A * B^T. A[M][K], B[N][K] bf16 row-major. BM=BN=256, BK=64, 8 waves
// (wr=wave>>2 in M, wc=wave&3 in N), per-wave 128x64 output = acc[8][4].
// LDS 128KB: per operand 2(dbuf) x 2(half of 128 rows) x [128][64] bf16,
// rows 128B swizzled byte^=((row&7)<<4) via pre-swizzled global source.
// Schedule (derived from the m201/HK template invariants):
//   8 phases per iteration, 2 K-tiles per iteration.
//   phase: {ds_read frags; stage 1 half (2xGLDS16); [vmcnt(6) @p0,p4];
//           barrier; 16 MFMA (setprio); barrier}
//   stage slots: p0:A(t1)h0 p1:A(t1)h1 p2:B(t0+2)h0 p3:B(t0+2)h1
//                p4:A(t0+2)h0 p5:A(t0+2)h1 p6:B(t1+2)h0 p7:B(t1+2)h1
//   Each wave reads only A-half(wr) and B-half(wc>>1); vmcnt(6) leaves exactly
//   the 3 newest halves (6 loads) in flight — never drains to 0 in the loop.
template <int OUT_BF16>
__global__ __launch_bounds__(512) void gemm_bt_256(
    const unsigned short* __restrict__ A,
    const unsigned short* __restrict__ B,
    void* __restrict__ Cv, int M, int N, int K) {
  __shared__ unsigned short As[2][2][8192];   // [buf][half][128*64]
  __shared__ unsigned short Bs[2][2][8192];
  const int tid = threadIdx.x;
  const int wave = tid >> 6;           // 0..7
  const int lane = tid & 63;
  const int l15 = lane & 15, l16 = lane >> 4;
  const int wr = wave >> 2;            // 0..1 (M)
  const int wc = wave & 3;             // 0..3 (N)

  // XCD-aware swizzle, bn-major so each XCD works on few B panels (L2 reuse)
  const int nby = M >> 8;                       // blocks in M
  const int nwg = gridDim.x * gridDim.y;        // % 8 == 0
  const int wg = blockIdx.y * gridDim.x + blockIdx.x;
  const int cpx = nwg >> 3;
  const int swz = (wg & 7) * cpx + (wg >> 3);
  const int bm = (swz % nby) * 256;
  const int bn = (swz / nby) * 256;

  // staging source geometry (inverse-swizzled, lane-pure)
  const int arow0 = wave * 8 + (lane >> 3);              // r=0 row (0..63)
  const int acol = (((lane & 7) * 16) ^ ((lane >> 3) << 4)) >> 1;  // elems
  const unsigned short* apan = A + (size_t)bm * K;
  const unsigned short* bpan = B + (size_t)bn * K;

#define STG(ARR, SRCP, BUF, H, KOFF)                                           \
  do {                                                                         \
    GLDS16(SRCP + (size_t)((H)*128 + arow0) * K + (KOFF) + acol,               \
           &ARR[BUF][H][wave * 512]);                                          \
    GLDS16(SRCP + (size_t)((H)*128 + 64 + arow0) * K + (KOFF) + acol,          \
           &ARR[BUF][H][4096 + wave * 512]);                                   \
  } while (0)

  f32x4 acc[8][4] = {};
  const char* Ah;   // this wave's A-half base (per buf set in loop)
  const char* Bh;

  const int NT = K / 64;           // 32
  const int NI = NT / 2;           // 16 iterations

  // prologue: B(0)h0,h1  A(0)h0,h1  B(1)h0,h1   (issue order matters for vmcnt)
  STG(Bs, bpan, 0, 0, 0); STG(Bs, bpan, 0, 1, 0);
  STG(As, apan, 0, 0, 0); STG(As, apan, 0, 1, 0);
  STG(Bs, bpan, 1, 0, 64); STG(Bs, bpan, 1, 1, 64);

  short8 bf[4][2];
  short8 af[2][2];

#define READ_A(BASE, MM0)                                                       \
  do {                                                                          \
    _Pragma("unroll") for (int mm = 0; mm < 2; ++mm)                            \
    _Pragma("unroll") for (int kk = 0; kk < 2; ++kk) {                          \
      int row = ((MM0) + mm) * 16 + l15;                                        \
      int cb = kk * 64 + l16 * 16;                                              \
      af[mm][kk] = *(const short8*)((BASE) + row * 128 + (cb ^ ((row & 7) << 4))); \
    }                                                                           \
  } while (0)

#define READ_B(BASE)                                                            \
  do {                                                                          \
    _Pragma("unroll") for (int n = 0; n < 4; ++n)                               \
    _Pragma("unroll") for (int kk = 0; kk < 2; ++kk) {                          \
      int row = (wc & 1) * 64 + n * 16 + l15;                                   \
      int cb = kk * 64 + l16 * 16;                                              \
      bf[n][kk] = *(const short8*)((BASE) + row * 128 + (cb ^ ((row & 7) << 4))); \
    }                                                                           \
  } while (0)

#define MFMA16X(MM0)                                                            \
  do {                                                                          \
    __builtin_amdgcn_s_setprio(1);                                              \
    _Pragma("unroll") for (int kk = 0; kk < 2; ++kk)                            \
    _Pragma("unroll") for (int mm = 0; mm < 2; ++mm)                            \
    _Pragma("unroll") for (int n = 0; n < 4; ++n)                               \
      acc[(MM0) + mm][n] = mfma16(af[mm][kk], bf[n][kk], acc[(MM0) + mm][n]);   \
    __builtin_amdgcn_s_setprio(0);                                              \
  } while (0)

#define BAR() __builtin_amdgcn_s_barrier()
#define VMCNT6() asm volatile("s_waitcnt vmcnt(6)" ::: "memory")

  for (int i = 0; i < NI; ++i) {
    const int k0 = i * 128;                       // t0 = 2i
    const int kA1 = k0 + 64;                      // t1
    const int kN0 = min(k0 + 128, K - 64);        // t0+2 (clamped last iter)
    const int kN1 = min(k0 + 192, K - 64);        // t1+2
    const int b0 = 0, b1 = 1;                     // tile parity buffers

    Ah = (const char*)As[b0][wr];
    Bh = (const char*)Bs[b0][wc >> 1];

    // ---- phase 0: stage A(t1)h0; vmcnt(6); bar; read B(t0)+A(t0)m0-1; mfma
    STG(As, apan, b1, 0, kA1);
    VMCNT6();
    BAR();
    READ_B(Bh);
    READ_A(Ah, 0);
    MFMA16X(0);
    BAR();
    // ---- phase 1: read A m2-3; stage A(t1)h1
    READ_A(Ah, 2);
    STG(As, apan, b1, 1, kA1);
    BAR();
    MFMA16X(2);
    BAR();
    // ---- phase 2: read A m4-5; stage B(t0+2)h0
    READ_A(Ah, 4);
    STG(Bs, bpan, b0, 0, kN0);
    BAR();
    MFMA16X(4);
    BAR();
    // ---- phase 3: read A m6-7; stage B(t0+2)h1
    READ_A(Ah, 6);
    STG(Bs, bpan, b0, 1, kN0);
    BAR();
    MFMA16X(6);
    BAR();

    Ah = (const char*)As[b1][wr];
    Bh = (const char*)Bs[b1][wc >> 1];

    // ---- phase 4: stage A(t0+2)h0; vmcnt(6); bar; read B(t1)+A(t1)m0-1; mfma
    STG(As, apan, b0, 0, kN0);
    VMCNT6();
    BAR();
    READ_B(Bh);
    READ_A(Ah, 0);
    MFMA16X(0);
    BAR();
    // ---- phase 5: read A m2-3; stage A(t0+2)h1
    READ_A(Ah, 2);
    STG(As, apan, b0, 1, kN0);
    BAR();
    MFMA16X(2);
    BAR();
    // ---- phase 6: read A m4-5; stage B(t1+2)h0
    READ_A(Ah, 4);
    STG(Bs, bpan, b1, 0, kN1);
    BAR();
    MFMA16X(4);
    BAR();
    // ---- phase 7: read A m6-7; stage B(t1+2)h1
    READ_A(Ah, 6);
    STG(Bs, bpan, b1, 1, kN1);
    BAR();
    MFMA16X(6);
    BAR();
  }
  asm volatile("s_waitcnt vmcnt(0)" ::: "memory");

  // epilogue
#pragma unroll
  for (int m = 0; m < 8; ++m)
#pragma unroll
    for (int n = 0; n < 4; ++n) {
      int row = bm + wr * 128 + m * 16 + l16 * 4;
      int col = bn + wc * 64 + n * 16 + l15;
#pragma unroll
      for (int j = 0; j < 4; ++j) {
        if (OUT_BF16)
          ((unsigned short*)Cv)[(size_t)(row + j) * N + col] = f2bf(acc[m][n][j]);
        else
          ((float*)Cv)[(size_t)(row + j) * N + col] = acc[m][n][j];
      }
    }
#undef STG
#undef READ_A
#undef READ_B
#undef MFMA16X
#undef BAR
#undef VMCNT6
}

// ---------------------------------------------------------------- GEMM 128x128 (m97)
template <int OUT_BF16>
__global__ __launch_bounds__(256) void gemm_bt_128(
    const unsigned short* __restrict__ A,
    const unsigned short* __restrict__ B,
    void* __restrict__ Cv, int M, int N, int K) {
  __shared__ unsigned short As[128 * 64];
  __shared__ unsigned short Bs[128 * 64];
  const int tid = threadIdx.x;
  const int wave = tid >> 6;
  const int lane = tid & 63;
  const int l15 = lane & 15, l16 = lane >> 4;
  const int bm = blockIdx.y * 128;
  const int bn = blockIdx.x * 128;
  const int wr = wave >> 1, wc = wave & 1;

  f32x4 acc[4][4] = {};

  int srow[4], scol[4];
#pragma unroll
  for (int i = 0; i < 4; ++i) {
    int lin = i * 4096 + tid * 16;
    int row = lin >> 7;
    int cb = lin & 127;
    srow[i] = row;
    scol[i] = (cb ^ ((row & 7) << 4)) >> 1;
  }

  for (int k0 = 0; k0 < K; k0 += 64) {
#pragma unroll
    for (int i = 0; i < 4; ++i) {
      GLDS16(A + (size_t)(bm + srow[i]) * K + k0 + scol[i], As + i * 2048 + wave * 512);
      GLDS16(B + (size_t)(bn + srow[i]) * K + k0 + scol[i], Bs + i * 2048 + wave * 512);
    }
    __syncthreads();
#pragma unroll
    for (int kk = 0; kk < 2; ++kk) {
      const int cb = kk * 64 + l16 * 16;
      short8 af[4], bfr[4];
#pragma unroll
      for (int m = 0; m < 4; ++m) {
        int row = wr * 64 + m * 16 + l15;
        af[m] = *(const short8*)((const char*)As + row * 128 + (cb ^ ((row & 7) << 4)));
      }
#pragma unroll
      for (int n = 0; n < 4; ++n) {
        int row = wc * 64 + n * 16 + l15;
        bfr[n] = *(const short8*)((const char*)Bs + row * 128 + (cb ^ ((row & 7) << 4)));
      }
#pragma unroll
      for (int m = 0; m < 4; ++m)
#pragma unroll
        for (int n = 0; n < 4; ++n)
          acc[m][n] = mfma16(af[m], bfr[n], acc[m][n]);
    }
    __syncthreads();
  }

#pragma unroll
  for (int m = 0; m < 4; ++m)
#pragma unroll
    for (int n = 0; n < 4; ++n) {
      int row = bm + wr * 64 + m * 16 + l16 * 4;
      int col = bn + wc * 64 + n * 16 + l15;
#pragma unroll
      for (int j = 0; j < 4; ++j) {
        if (OUT_BF16)
          ((unsigned short*)Cv)[(size_t)(row + j) * N + col] = f2bf(acc[m][n][j]);
        else
          ((float*)Cv)[(size_t)(row + j) * N + col] = acc[m][n][j];
      }
    }
}

// ---------------------------------------------------------------- V transpose
__global__ __launch_bounds__(256) void transpose_v(
    const unsigned short* __restrict__ qkv, unsigned short* __restrict__ vt) {
  __shared__ unsigned short t[64 * 128];
  const int tid = threadIdx.x;
  const int h = blockIdx.y;
  const int s0 = blockIdx.x * 64;
#pragma unroll
  for (int i = 0; i < 4; ++i) {
    int lin = i * 2048 + tid * 8;
    int row = lin >> 7, col = lin & 127;
    char* dst = (char*)t + row * 256 + ((col * 2) ^ (((row >> 3) & 7) << 4));
    *(short8*)dst =
        *(const short8*)(qkv + (size_t)(s0 + row) * QKV_LD + 2 * DIM + h * HD + col);
  }
  __syncthreads();
#pragma unroll
  for (int i2 = 0; i2 < 4; ++i2) {
    int d = (tid >> 3) + i2 * 32;
    int sb = (tid & 7) * 8;
    short8 v;
#pragma unroll
    for (int j = 0; j < 8; ++j) {
      int s = sb + j;
      v[j] = *(const short*)((const char*)t + s * 256 + ((d * 2) ^ (((s >> 3) & 7) << 4)));
    }
    *(short8*)(vt + ((size_t)h * HD + d) * T_LEN + s0 + sb) = v;
  }
}

// ---------------------------------------------------------------- flash attention
// R3-exact structure (best measured: 81.5us): 4 waves x 16q, KV tile 64,
// double-buffered, prefetch-before-compute, one barrier/iter. Plus R4's
// XCD swizzle (FETCH 5.7x down, proven) and T5 setprio around MFMA clusters.
__global__ __launch_bounds__(256) void attn_fwd(
    const unsigned short* __restrict__ qkv,
    const unsigned short* __restrict__ vt,
    unsigned short* __restrict__ ctx) {
  __shared__ unsigned short Ks[2][64 * 128];
  __shared__ unsigned short Vs[2][128 * 64];
  __shared__ unsigned short Ps[4 * 16 * 64];
  const int tid = threadIdx.x;
  const int wave = tid >> 6;
  const int lane = tid & 63;
  const int l15 = lane & 15, l16 = lane >> 4;

  // XCD swizzle: 512 wgs % 8 == 0 -> bijective; XCD x gets heads {2x,2x+1}
  const int wg = blockIdx.y * 32 + blockIdx.x;
  const int swz = (wg & 7) * 64 + (wg >> 3);
  const int h = swz >> 5;
  const int q0 = (swz & 31) * 64 + wave * 16;
  const float SCL = 0.08838834764831845f * 1.4426950408889634f;  // 1/sqrt(128)*log2(e)

  short8 qf[4];
#pragma unroll
  for (int kk = 0; kk < 4; ++kk)
    qf[kk] = *(const short8*)(qkv + (size_t)(q0 + l15) * QKV_LD + h * HD + kk * 32 + l16 * 8);

  f32x4 acc_o[8] = {};
  float m_r = -1e30f;
  float l_r = 0.f;

  int krow[4], kcol[4], vrow[4], vcol[4];
#pragma unroll
  for (int i = 0; i < 4; ++i) {
    int lin = i * 4096 + tid * 16;
    int r = lin >> 8;
    int cb = lin & 255;
    krow[i] = r; kcol[i] = (cb ^ ((r & 7) << 4)) >> 1;
    r = lin >> 7;
    cb = lin & 127;
    vrow[i] = r; vcol[i] = (cb ^ ((r & 7) << 4)) >> 1;
  }
  const unsigned short* kbase = qkv + 2048 + h * HD;
  const unsigned short* vbase = vt + (size_t)h * HD * T_LEN;

#define STAGE_KV(BUF, S0)                                                              \
  do {                                                                                 \
    _Pragma("unroll")                                                                  \
    for (int i = 0; i < 4; ++i) {                                                      \
      GLDS16(kbase + (size_t)((S0) + krow[i]) * QKV_LD + kcol[i],                      \
             Ks[BUF] + i * 2048 + wave * 512);                                         \
      GLDS16(vbase + (size_t)vrow[i] * T_LEN + (S0) + vcol[i],                         \
             Vs[BUF] + i * 2048 + wave * 512);                                         \
    }                                                                                  \
  } while (0)

  STAGE_KV(0, 0);
  __syncthreads();

  const int NT = T_LEN / 64;
  int cur = 0;
  for (int t = 0; t < NT; ++t) {
    if (t + 1 < NT) STAGE_KV(cur ^ 1, (t + 1) * 64);

    const unsigned short* ks = Ks[cur];
    const unsigned short* vs = Vs[cur];

    // S^T = K Q^T : lane (l15,l16) holds S[kv = c*16 + l16*4 + j][q = l15]
    f32x4 st[4] = {};
    __builtin_amdgcn_s_setprio(1);
#pragma unroll
    for (int c = 0; c < 4; ++c) {
#pragma unroll
      for (int kk = 0; kk < 4; ++kk) {
        int row = c * 16 + l15;
        int cb = kk * 64 + l16 * 16;
        short8 kf = *(const short8*)((const char*)ks + row * 256 + (cb ^ ((row & 7) << 4)));
        st[c] = mfma16(kf, qf[kk], st[c]);
      }
    }
    __builtin_amdgcn_s_setprio(0);

    // online softmax, lane-local for q-row l15
    float ma = max3f(st[0][0], st[0][1], st[0][2]);
    float mb = max3f(st[0][3], st[1][0], st[1][1]);
    float mc = max3f(st[1][2], st[1][3], st[2][0]);
    float md = max3f(st[2][1], st[2][2], st[2][3]);
    float me = max3f(st[3][0], st[3][1], st[3][2]);
    float pmax = fmaxf(max3f(ma, mb, mc), max3f(md, me, st[3][3])) * SCL;
    pmax = fmaxf(pmax, __shfl_xor(pmax, 16));
    pmax = fmaxf(pmax, __shfl_xor(pmax, 32));

    if (!__all(pmax - m_r <= 8.0f)) {
      float nm = fmaxf(m_r, pmax);
      float corr = __builtin_amdgcn_exp2f(m_r - nm);
      m_r = nm;
      l_r *= corr;
      float cj[4];
#pragma unroll
      for (int j = 0; j < 4; ++j) cj[j] = __shfl(corr, l16 * 4 + j);
#pragma unroll
      for (int d = 0; d < 8; ++d)
#pragma unroll
        for (int j = 0; j < 4; ++j) acc_o[d][j] *= cj[j];
    }

    float p[4][4];
#pragma unroll
    for (int c = 0; c < 4; ++c)
#pragma unroll
      for (int j = 0; j < 4; ++j)
        p[c][j] = __builtin_amdgcn_exp2f(st[c][j] * SCL - m_r);
    float s01 = (p[0][0] + p[0][1]) + (p[0][2] + p[0][3]);
    float s23 = (p[1][0] + p[1][1]) + (p[1][2] + p[1][3]);
    float s45 = (p[2][0] + p[2][1]) + (p[2][2] + p[2][3]);
    float s67 = (p[3][0] + p[3][1]) + (p[3][2] + p[3][3]);
    float tsum = (s01 + s23) + (s45 + s67);
    tsum += __shfl_xor(tsum, 16);
    tsum += __shfl_xor(tsum, 32);
    l_r += tsum;

    char* pbase = (char*)Ps + wave * 2048;
#pragma unroll
    for (int c = 0; c < 4; ++c) {
      uint2v w;
      w.x = (unsigned)f2bf(p[c][0]) | ((unsigned)f2bf(p[c][1]) << 16);
      w.y = (unsigned)f2bf(p[c][2]) | ((unsigned)f2bf(p[c][3]) << 16);
      int off = l15 * 128 + c * 32 + l16 * 8;
      *(uint2v*)(pbase + (off ^ ((l15 & 7) << 4))) = w;
    }

    __builtin_amdgcn_s_setprio(1);
#pragma unroll
    for (int kk = 0; kk < 2; ++kk) {
      int cb = kk * 64 + l16 * 16;
      short8 pa = *(const short8*)(pbase + l15 * 128 + (cb ^ ((l15 & 7) << 4)));
#pragma unroll
      for (int d = 0; d < 8; ++d) {
        int row = d * 16 + l15;
        short8 vb = *(const short8*)((const char*)vs + row * 128 + (cb ^ ((row & 7) << 4)));
        acc_o[d] = mfma16(pa, vb, acc_o[d]);
      }
    }
    __builtin_amdgcn_s_setprio(0);

    __syncthreads();
    cur ^= 1;
  }
#undef STAGE_KV

  float lq[4];
#pragma unroll
  for (int j = 0; j < 4; ++j) lq[j] = 1.0f / __shfl(l_r, l16 * 4 + j);
#pragma unroll
  for (int d = 0; d < 8; ++d)
#pragma unroll
    for (int j = 0; j < 4; ++j) {
      int row = q0 + l16 * 4 + j;
      int col = h * HD + d * 16 + l15;
      ctx[(size_t)row * DIM + col] = f2bf(acc_o[d][j] * lq[j]);
    }
}

// ---------------------------------------------------------------- launcher
extern "C" void kernel_launch(void* const* d_in, const int* in_sizes, int n_in,
                              void* d_out, int out_size, void* d_ws, size_t ws_size,
                              hipStream_t stream) {
  const float* x = (const float*)d_in[0];
  const float* w_in = (const float*)d_in[1];
  const float* w_out = (const float*)d_in[2];

  char* ws = (char*)d_ws;
  unsigned short* xbf  = (unsigned short*)(ws + 0);          //  8 MB
  unsigned short* wibf = (unsigned short*)(ws + 8388608);    // 24 MB
  unsigned short* wobf = (unsigned short*)(ws + 33554432);   //  8 MB
  unsigned short* qkv  = (unsigned short*)(ws + 41943040);   // 24 MB
  unsigned short* ctx  = (unsigned short*)(ws + 67108864);   //  8 MB
  unsigned short* vt   = (unsigned short*)(ws + 75497472);   //  8 MB  (end: 80 MB)

  cast_f32_bf16<<<2048, 256, 0, stream>>>(x, xbf, (T_LEN * DIM) / 4);
  cast_f32_bf16<<<2048, 256, 0, stream>>>(w_in, wibf, (3 * DIM * DIM) / 4);
  cast_f32_bf16<<<2048, 256, 0, stream>>>(w_out, wobf, (DIM * DIM) / 4);

  // qkv = x @ w_in^T   [2048 x 6144] — 256x256 8-phase kernel, 192 blocks
  gemm_bt_256<1><<<dim3(24, 8), 512, 0, stream>>>(xbf, wibf, (void*)qkv, T_LEN, 3 * DIM, DIM);
  // vt[h][d][s] = V
  transpose_v<<<dim3(32, 16), 256, 0, stream>>>(qkv, vt);
  // attention -> ctx [2048 x 2048] bf16
  attn_fwd<<<dim3(32, 16), 256, 0, stream>>>(qkv, vt, ctx);
  // out = ctx @ w_out^T  (fp32)
  gemm_bt_128<0><<<dim3(16, 16), 256, 0, stream>>>(ctx, wobf, d_out, T_LEN, DIM, DIM);
}

// Round 8
// 186.672 us; speedup vs baseline: 1.1463x; 1.1170x over previous
//
#include <hip/hip_runtime.h>

#define T_LEN 2048
#define DIM 2048
#define NH 16
#define HD 128
#define QKV_LD 6144   // 3*DIM

typedef __attribute__((ext_vector_type(8))) short short8;
typedef __attribute__((ext_vector_type(4))) float f32x4;
typedef __attribute__((ext_vector_type(4))) float float4v;
typedef __attribute__((ext_vector_type(4))) unsigned short ushort4v;
typedef __attribute__((ext_vector_type(2))) unsigned int uint2v;

static __device__ __forceinline__ unsigned short f2bf(float f) {
  unsigned u = __builtin_bit_cast(unsigned, f);
  u += 0x7fffu + ((u >> 16) & 1u);   // round-to-nearest-even
  return (unsigned short)(u >> 16);
}

static __device__ __forceinline__ float max3f(float a, float b, float c) {
  return fmaxf(fmaxf(a, b), c);      // clang fuses to v_max3_f32
}

static __device__ __forceinline__ f32x4 mfma16(short8 a, short8 b, f32x4 c) {
  return __builtin_amdgcn_mfma_f32_16x16x32_bf16(a, b, c, 0, 0, 0);
}

#define GLDS16(SRC, DST)                                                            \
  __builtin_amdgcn_global_load_lds((__attribute__((address_space(1))) void*)(SRC),  \
                                   (__attribute__((address_space(3))) void*)(DST),  \
                                   16, 0, 0)

// ---------------------------------------------------------------- fused casts
// One launch for all three fp32->bf16 casts (saves 2 graph-replay launch gaps).
__global__ void cast3_f32_bf16(const float* __restrict__ a, unsigned short* __restrict__ oa, int na4,
                               const float* __restrict__ b, unsigned short* __restrict__ ob, int nb4,
                               const float* __restrict__ c, unsigned short* __restrict__ oc, int nc4) {
  const int stride = gridDim.x * blockDim.x;
  const int g = blockIdx.x * blockDim.x + threadIdx.x;
#define CAST_LOOP(SRC, DST, N4)                                  \
  for (int i = g; i < (N4); i += stride) {                       \
    float4v f = ((const float4v*)(SRC))[i];                      \
    ushort4v o;                                                  \
    o.x = f2bf(f.x); o.y = f2bf(f.y);                            \
    o.z = f2bf(f.z); o.w = f2bf(f.w);                            \
    ((ushort4v*)(DST))[i] = o;                                   \
  }
  CAST_LOOP(a, oa, na4)
  CAST_LOOP(b, ob, nb4)
  CAST_LOOP(c, oc, nc4)
#undef CAST_LOOP
}

// ---------------------------------------------------------------- GEMM 128x128 (m97)
// C = A * B^T. A[M][K], B[N][K] bf16 row-major, C [M][N] (bf16 or f32).
// BK=64, 4 waves (each 64x64), global_load_lds staging, swizzled LDS rows.
template <int OUT_BF16>
__global__ __launch_bounds__(256) void gemm_bt_128(
    const unsigned short* __restrict__ A,
    const unsigned short* __restrict__ B,
    void* __restrict__ Cv, int M, int N, int K) {
  __shared__ unsigned short As[128 * 64];
  __shared__ unsigned short Bs[128 * 64];
  const int tid = threadIdx.x;
  const int wave = tid >> 6;
  const int lane = tid & 63;
  const int l15 = lane & 15, l16 = lane >> 4;
  const int bm = blockIdx.y * 128;
  const int bn = blockIdx.x * 128;
  const int wr = wave >> 1, wc = wave & 1;

  f32x4 acc[4][4] = {};

  int srow[4], scol[4];
#pragma unroll
  for (int i = 0; i < 4; ++i) {
    int lin = i * 4096 + tid * 16;
    int row = lin >> 7;
    int cb = lin & 127;
    srow[i] = row;
    scol[i] = (cb ^ ((row & 7) << 4)) >> 1;
  }

  for (int k0 = 0; k0 < K; k0 += 64) {
#pragma unroll
    for (int i = 0; i < 4; ++i) {
      GLDS16(A + (size_t)(bm + srow[i]) * K + k0 + scol[i], As + i * 2048 + wave * 512);
      GLDS16(B + (size_t)(bn + srow[i]) * K + k0 + scol[i], Bs + i * 2048 + wave * 512);
    }
    __syncthreads();
#pragma unroll
    for (int kk = 0; kk < 2; ++kk) {
      const int cb = kk * 64 + l16 * 16;
      short8 af[4], bfr[4];
#pragma unroll
      for (int m = 0; m < 4; ++m) {
        int row = wr * 64 + m * 16 + l15;
        af[m] = *(const short8*)((const char*)As + row * 128 + (cb ^ ((row & 7) << 4)));
      }
#pragma unroll
      for (int n = 0; n < 4; ++n) {
        int row = wc * 64 + n * 16 + l15;
        bfr[n] = *(const short8*)((const char*)Bs + row * 128 + (cb ^ ((row & 7) << 4)));
      }
#pragma unroll
      for (int m = 0; m < 4; ++m)
#pragma unroll
        for (int n = 0; n < 4; ++n)
          acc[m][n] = mfma16(af[m], bfr[n], acc[m][n]);
    }
    __syncthreads();
  }

#pragma unroll
  for (int m = 0; m < 4; ++m)
#pragma unroll
    for (int n = 0; n < 4; ++n) {
      int row = bm + wr * 64 + m * 16 + l16 * 4;
      int col = bn + wc * 64 + n * 16 + l15;
#pragma unroll
      for (int j = 0; j < 4; ++j) {
        if (OUT_BF16)
          ((unsigned short*)Cv)[(size_t)(row + j) * N + col] = f2bf(acc[m][n][j]);
        else
          ((float*)Cv)[(size_t)(row + j) * N + col] = acc[m][n][j];
      }
    }
}

// ---------------------------------------------------------------- V transpose
__global__ __launch_bounds__(256) void transpose_v(
    const unsigned short* __restrict__ qkv, unsigned short* __restrict__ vt) {
  __shared__ unsigned short t[64 * 128];
  const int tid = threadIdx.x;
  const int h = blockIdx.y;
  const int s0 = blockIdx.x * 64;
#pragma unroll
  for (int i = 0; i < 4; ++i) {
    int lin = i * 2048 + tid * 8;
    int row = lin >> 7, col = lin & 127;
    char* dst = (char*)t + row * 256 + ((col * 2) ^ (((row >> 3) & 7) << 4));
    *(short8*)dst =
        *(const short8*)(qkv + (size_t)(s0 + row) * QKV_LD + 2 * DIM + h * HD + col);
  }
  __syncthreads();
#pragma unroll
  for (int i2 = 0; i2 < 4; ++i2) {
    int d = (tid >> 3) + i2 * 32;
    int sb = (tid & 7) * 8;
    short8 v;
#pragma unroll
    for (int j = 0; j < 8; ++j) {
      int s = sb + j;
      v[j] = *(const short*)((const char*)t + s * 256 + ((d * 2) ^ (((s >> 3) & 7) << 4)));
    }
    *(short8*)(vt + ((size_t)h * HD + d) * T_LEN + s0 + sb) = v;
  }
}

// ---------------------------------------------------------------- flash attention
// R3-exact structure (best measured): 4 waves x 16q, KV tile 64, double-
// buffered, prefetch-before-compute, one barrier/iter. R4 XCD swizzle
// (FETCH 5.7x down) + T5 setprio around MFMA clusters.
__global__ __launch_bounds__(256) void attn_fwd(
    const unsigned short* __restrict__ qkv,
    const unsigned short* __restrict__ vt,
    unsigned short* __restrict__ ctx) {
  __shared__ unsigned short Ks[2][64 * 128];
  __shared__ unsigned short Vs[2][128 * 64];
  __shared__ unsigned short Ps[4 * 16 * 64];
  const int tid = threadIdx.x;
  const int wave = tid >> 6;
  const int lane = tid & 63;
  const int l15 = lane & 15, l16 = lane >> 4;

  // XCD swizzle: 512 wgs % 8 == 0 -> bijective; XCD x gets heads {2x,2x+1}
  const int wg = blockIdx.y * 32 + blockIdx.x;
  const int swz = (wg & 7) * 64 + (wg >> 3);
  const int h = swz >> 5;
  const int q0 = (swz & 31) * 64 + wave * 16;
  const float SCL = 0.08838834764831845f * 1.4426950408889634f;  // 1/sqrt(128)*log2(e)

  short8 qf[4];
#pragma unroll
  for (int kk = 0; kk < 4; ++kk)
    qf[kk] = *(const short8*)(qkv + (size_t)(q0 + l15) * QKV_LD + h * HD + kk * 32 + l16 * 8);

  f32x4 acc_o[8] = {};
  float m_r = -1e30f;
  float l_r = 0.f;

  int krow[4], kcol[4], vrow[4], vcol[4];
#pragma unroll
  for (int i = 0; i < 4; ++i) {
    int lin = i * 4096 + tid * 16;
    int r = lin >> 8;
    int cb = lin & 255;
    krow[i] = r; kcol[i] = (cb ^ ((r & 7) << 4)) >> 1;
    r = lin >> 7;
    cb = lin & 127;
    vrow[i] = r; vcol[i] = (cb ^ ((r & 7) << 4)) >> 1;
  }
  const unsigned short* kbase = qkv + 2048 + h * HD;
  const unsigned short* vbase = vt + (size_t)h * HD * T_LEN;

#define STAGE_KV(BUF, S0)                                                              \
  do {                                                                                 \
    _Pragma("unroll")                                                                  \
    for (int i = 0; i < 4; ++i) {                                                      \
      GLDS16(kbase + (size_t)((S0) + krow[i]) * QKV_LD + kcol[i],                      \
             Ks[BUF] + i * 2048 + wave * 512);                                         \
      GLDS16(vbase + (size_t)vrow[i] * T_LEN + (S0) + vcol[i],                         \
             Vs[BUF] + i * 2048 + wave * 512);                                         \
    }                                                                                  \
  } while (0)

  STAGE_KV(0, 0);
  __syncthreads();

  const int NT = T_LEN / 64;
  int cur = 0;
  for (int t = 0; t < NT; ++t) {
    if (t + 1 < NT) STAGE_KV(cur ^ 1, (t + 1) * 64);

    const unsigned short* ks = Ks[cur];
    const unsigned short* vs = Vs[cur];

    // S^T = K Q^T : lane (l15,l16) holds S[kv = c*16 + l16*4 + j][q = l15]
    f32x4 st[4] = {};
    __builtin_amdgcn_s_setprio(1);
#pragma unroll
    for (int c = 0; c < 4; ++c) {
#pragma unroll
      for (int kk = 0; kk < 4; ++kk) {
        int row = c * 16 + l15;
        int cb = kk * 64 + l16 * 16;
        short8 kf = *(const short8*)((const char*)ks + row * 256 + (cb ^ ((row & 7) << 4)));
        st[c] = mfma16(kf, qf[kk], st[c]);
      }
    }
    __builtin_amdgcn_s_setprio(0);

    // online softmax, lane-local for q-row l15
    float ma = max3f(st[0][0], st[0][1], st[0][2]);
    float mb = max3f(st[0][3], st[1][0], st[1][1]);
    float mc = max3f(st[1][2], st[1][3], st[2][0]);
    float md = max3f(st[2][1], st[2][2], st[2][3]);
    float me = max3f(st[3][0], st[3][1], st[3][2]);
    float pmax = fmaxf(max3f(ma, mb, mc), max3f(md, me, st[3][3])) * SCL;
    pmax = fmaxf(pmax, __shfl_xor(pmax, 16));
    pmax = fmaxf(pmax, __shfl_xor(pmax, 32));

    if (!__all(pmax - m_r <= 8.0f)) {
      float nm = fmaxf(m_r, pmax);
      float corr = __builtin_amdgcn_exp2f(m_r - nm);
      m_r = nm;
      l_r *= corr;
      float cj[4];
#pragma unroll
      for (int j = 0; j < 4; ++j) cj[j] = __shfl(corr, l16 * 4 + j);
#pragma unroll
      for (int d = 0; d < 8; ++d)
#pragma unroll
        for (int j = 0; j < 4; ++j) acc_o[d][j] *= cj[j];
    }

    float p[4][4];
#pragma unroll
    for (int c = 0; c < 4; ++c)
#pragma unroll
      for (int j = 0; j < 4; ++j)
        p[c][j] = __builtin_amdgcn_exp2f(st[c][j] * SCL - m_r);
    float s01 = (p[0][0] + p[0][1]) + (p[0][2] + p[0][3]);
    float s23 = (p[1][0] + p[1][1]) + (p[1][2] + p[1][3]);
    float s45 = (p[2][0] + p[2][1]) + (p[2][2] + p[2][3]);
    float s67 = (p[3][0] + p[3][1]) + (p[3][2] + p[3][3]);
    float tsum = (s01 + s23) + (s45 + s67);
    tsum += __shfl_xor(tsum, 16);
    tsum += __shfl_xor(tsum, 32);
    l_r += tsum;

    char* pbase = (char*)Ps + wave * 2048;
#pragma unroll
    for (int c = 0; c < 4; ++c) {
      uint2v w;
      w.x = (unsigned)f2bf(p[c][0]) | ((unsigned)f2bf(p[c][1]) << 16);
      w.y = (unsigned)f2bf(p[c][2]) | ((unsigned)f2bf(p[c][3]) << 16);
      int off = l15 * 128 + c * 32 + l16 * 8;
      *(uint2v*)(pbase + (off ^ ((l15 & 7) << 4))) = w;
    }

    __builtin_amdgcn_s_setprio(1);
#pragma unroll
    for (int kk = 0; kk < 2; ++kk) {
      int cb = kk * 64 + l16 * 16;
      short8 pa = *(const short8*)(pbase + l15 * 128 + (cb ^ ((l15 & 7) << 4)));
#pragma unroll
      for (int d = 0; d < 8; ++d) {
        int row = d * 16 + l15;
        short8 vb = *(const short8*)((const char*)vs + row * 128 + (cb ^ ((row & 7) << 4)));
        acc_o[d] = mfma16(pa, vb, acc_o[d]);
      }
    }
    __builtin_amdgcn_s_setprio(0);

    __syncthreads();
    cur ^= 1;
  }
#undef STAGE_KV

  float lq[4];
#pragma unroll
  for (int j = 0; j < 4; ++j) lq[j] = 1.0f / __shfl(l_r, l16 * 4 + j);
#pragma unroll
  for (int d = 0; d < 8; ++d)
#pragma unroll
    for (int j = 0; j < 4; ++j) {
      int row = q0 + l16 * 4 + j;
      int col = h * HD + d * 16 + l15;
      ctx[(size_t)row * DIM + col] = f2bf(acc_o[d][j] * lq[j]);
    }
}

// ---------------------------------------------------------------- launcher
extern "C" void kernel_launch(void* const* d_in, const int* in_sizes, int n_in,
                              void* d_out, int out_size, void* d_ws, size_t ws_size,
                              hipStream_t stream) {
  const float* x = (const float*)d_in[0];
  const float* w_in = (const float*)d_in[1];
  const float* w_out = (const float*)d_in[2];

  char* ws = (char*)d_ws;
  unsigned short* xbf  = (unsigned short*)(ws + 0);          //  8 MB
  unsigned short* wibf = (unsigned short*)(ws + 8388608);    // 24 MB
  unsigned short* wobf = (unsigned short*)(ws + 33554432);   //  8 MB
  unsigned short* qkv  = (unsigned short*)(ws + 41943040);   // 24 MB
  unsigned short* ctx  = (unsigned short*)(ws + 67108864);   //  8 MB
  unsigned short* vt   = (unsigned short*)(ws + 75497472);   //  8 MB  (end: 80 MB)

  // fused fp32->bf16 casts (x, w_in, w_out) in one launch
  cast3_f32_bf16<<<2048, 256, 0, stream>>>(
      x, xbf, (T_LEN * DIM) / 4,
      w_in, wibf, (3 * DIM * DIM) / 4,
      w_out, wobf, (DIM * DIM) / 4);

  // qkv = x @ w_in^T   [2048 x 6144]
  gemm_bt_128<1><<<dim3(48, 16), 256, 0, stream>>>(xbf, wibf, (void*)qkv, T_LEN, 3 * DIM, DIM);
  // vt[h][d][s] = V
  transpose_v<<<dim3(32, 16), 256, 0, stream>>>(qkv, vt);
  // attention -> ctx [2048 x 2048] bf16
  attn_fwd<<<dim3(32, 16), 256, 0, stream>>>(qkv, vt, ctx);
  // out = ctx @ w_out^T  (fp32)
  gemm_bt_128<0><<<dim3(16, 16), 256, 0, stream>>>(ctx, wobf, d_out, T_LEN, DIM, DIM);
}

// Round 9
// 183.016 us; speedup vs baseline: 1.1692x; 1.0200x over previous
//
#include <hip/hip_runtime.h>

#define T_LEN 2048
#define DIM 2048
#define NH 16
#define HD 128
#define QKV_LD 6144   // 3*DIM

typedef __attribute__((ext_vector_type(8))) short short8;
typedef __attribute__((ext_vector_type(4))) short short4v;
typedef __attribute__((ext_vector_type(4))) float f32x4;
typedef __attribute__((ext_vector_type(4))) float float4v;
typedef __attribute__((ext_vector_type(4))) unsigned short ushort4v;
typedef __attribute__((ext_vector_type(2))) unsigned int uint2v;

static __device__ __forceinline__ unsigned short f2bf(float f) {
  unsigned u = __builtin_bit_cast(unsigned, f);
  u += 0x7fffu + ((u >> 16) & 1u);   // round-to-nearest-even
  return (unsigned short)(u >> 16);
}

static __device__ __forceinline__ float max3f(float a, float b, float c) {
  return fmaxf(fmaxf(a, b), c);      // clang fuses to v_max3_f32
}

static __device__ __forceinline__ f32x4 mfma16(short8 a, short8 b, f32x4 c) {
  return __builtin_amdgcn_mfma_f32_16x16x32_bf16(a, b, c, 0, 0, 0);
}

#define GLDS16(SRC, DST)                                                            \
  __builtin_amdgcn_global_load_lds((__attribute__((address_space(1))) void*)(SRC),  \
                                   (__attribute__((address_space(3))) void*)(DST),  \
                                   16, 0, 0)

// ---------------------------------------------------------------- fused casts
__global__ void cast3_f32_bf16(const float* __restrict__ a, unsigned short* __restrict__ oa, int na4,
                               const float* __restrict__ b, unsigned short* __restrict__ ob, int nb4,
                               const float* __restrict__ c, unsigned short* __restrict__ oc, int nc4) {
  const int stride = gridDim.x * blockDim.x;
  const int g = blockIdx.x * blockDim.x + threadIdx.x;
#define CAST_LOOP(SRC, DST, N4)                                  \
  for (int i = g; i < (N4); i += stride) {                       \
    float4v f = ((const float4v*)(SRC))[i];                      \
    ushort4v o;                                                  \
    o.x = f2bf(f.x); o.y = f2bf(f.y);                            \
    o.z = f2bf(f.z); o.w = f2bf(f.w);                            \
    ((ushort4v*)(DST))[i] = o;                                   \
  }
  CAST_LOOP(a, oa, na4)
  CAST_LOOP(b, ob, nb4)
  CAST_LOOP(c, oc, nc4)
#undef CAST_LOOP
}

// ---------------------------------------------------------------- GEMM 128x128 (m97)
// C = A * B^T. A[M][K], B[N][K] bf16 row-major.
// MODE 0: C f32 row-major. MODE 1: C bf16 row-major.
// MODE 2 (qkv fused): Q/K thirds (col < 2*DIM) -> bf16 row-major into Cv;
//                     V third (col >= 2*DIM)   -> TRANSPOSED bf16 into
//                     vt[(col-2*DIM)*T_LEN + row] (i.e. vt[h][d][s]),
//                     j-contiguous -> one short4 store per fragment.
template <int MODE>
__global__ __launch_bounds__(256) void gemm_bt_128(
    const unsigned short* __restrict__ A,
    const unsigned short* __restrict__ B,
    void* __restrict__ Cv, unsigned short* __restrict__ vt,
    int M, int N, int K) {
  __shared__ unsigned short As[128 * 64];
  __shared__ unsigned short Bs[128 * 64];
  const int tid = threadIdx.x;
  const int wave = tid >> 6;
  const int lane = tid & 63;
  const int l15 = lane & 15, l16 = lane >> 4;
  const int bm = blockIdx.y * 128;
  const int bn = blockIdx.x * 128;
  const int wr = wave >> 1, wc = wave & 1;

  f32x4 acc[4][4] = {};

  int srow[4], scol[4];
#pragma unroll
  for (int i = 0; i < 4; ++i) {
    int lin = i * 4096 + tid * 16;
    int row = lin >> 7;
    int cb = lin & 127;
    srow[i] = row;
    scol[i] = (cb ^ ((row & 7) << 4)) >> 1;
  }

  for (int k0 = 0; k0 < K; k0 += 64) {
#pragma unroll
    for (int i = 0; i < 4; ++i) {
      GLDS16(A + (size_t)(bm + srow[i]) * K + k0 + scol[i], As + i * 2048 + wave * 512);
      GLDS16(B + (size_t)(bn + srow[i]) * K + k0 + scol[i], Bs + i * 2048 + wave * 512);
    }
    __syncthreads();
#pragma unroll
    for (int kk = 0; kk < 2; ++kk) {
      const int cb = kk * 64 + l16 * 16;
      short8 af[4], bfr[4];
#pragma unroll
      for (int m = 0; m < 4; ++m) {
        int row = wr * 64 + m * 16 + l15;
        af[m] = *(const short8*)((const char*)As + row * 128 + (cb ^ ((row & 7) << 4)));
      }
#pragma unroll
      for (int n = 0; n < 4; ++n) {
        int row = wc * 64 + n * 16 + l15;
        bfr[n] = *(const short8*)((const char*)Bs + row * 128 + (cb ^ ((row & 7) << 4)));
      }
#pragma unroll
      for (int m = 0; m < 4; ++m)
#pragma unroll
        for (int n = 0; n < 4; ++n)
          acc[m][n] = mfma16(af[m], bfr[n], acc[m][n]);
    }
    __syncthreads();
  }

  // epilogue: C/D layout col=lane&15, row=(lane>>4)*4+j  [m89-verified]
  const bool vthird = (MODE == 2) && (bn >= 2 * DIM);   // wave-uniform
#pragma unroll
  for (int m = 0; m < 4; ++m)
#pragma unroll
    for (int n = 0; n < 4; ++n) {
      int row = bm + wr * 64 + m * 16 + l16 * 4;
      int col = bn + wc * 64 + n * 16 + l15;
      if (MODE == 2 && vthird) {
        // transposed V write: vt[(col-2*DIM)*T_LEN + row .. +3]
        short4v w;
#pragma unroll
        for (int j = 0; j < 4; ++j) w[j] = (short)f2bf(acc[m][n][j]);
        *(short4v*)(vt + (size_t)(col - 2 * DIM) * T_LEN + row) = w;
      } else {
#pragma unroll
        for (int j = 0; j < 4; ++j) {
          if (MODE == 0)
            ((float*)Cv)[(size_t)(row + j) * N + col] = acc[m][n][j];
          else
            ((unsigned short*)Cv)[(size_t)(row + j) * N + col] = f2bf(acc[m][n][j]);
        }
      }
    }
}

// ---------------------------------------------------------------- flash attention
// R3-exact structure: 4 waves x 16q, KV tile 64, double-buffered, prefetch-
// before-compute, one barrier/iter. + R4 XCD swizzle (FETCH 5.7x down).
// NO setprio this round (isolation: m190 says null/negative for barrier-
// synced lockstep waves, which is our structure).
__global__ __launch_bounds__(256) void attn_fwd(
    const unsigned short* __restrict__ qkv,
    const unsigned short* __restrict__ vt,
    unsigned short* __restrict__ ctx) {
  __shared__ unsigned short Ks[2][64 * 128];
  __shared__ unsigned short Vs[2][128 * 64];
  __shared__ unsigned short Ps[4 * 16 * 64];
  const int tid = threadIdx.x;
  const int wave = tid >> 6;
  const int lane = tid & 63;
  const int l15 = lane & 15, l16 = lane >> 4;

  // XCD swizzle: 512 wgs % 8 == 0 -> bijective; XCD x gets heads {2x,2x+1}
  const int wg = blockIdx.y * 32 + blockIdx.x;
  const int swz = (wg & 7) * 64 + (wg >> 3);
  const int h = swz >> 5;
  const int q0 = (swz & 31) * 64 + wave * 16;
  const float SCL = 0.08838834764831845f * 1.4426950408889634f;  // 1/sqrt(128)*log2(e)

  short8 qf[4];
#pragma unroll
  for (int kk = 0; kk < 4; ++kk)
    qf[kk] = *(const short8*)(qkv + (size_t)(q0 + l15) * QKV_LD + h * HD + kk * 32 + l16 * 8);

  f32x4 acc_o[8] = {};
  float m_r = -1e30f;
  float l_r = 0.f;

  int krow[4], kcol[4], vrow[4], vcol[4];
#pragma unroll
  for (int i = 0; i < 4; ++i) {
    int lin = i * 4096 + tid * 16;
    int r = lin >> 8;
    int cb = lin & 255;
    krow[i] = r; kcol[i] = (cb ^ ((r & 7) << 4)) >> 1;
    r = lin >> 7;
    cb = lin & 127;
    vrow[i] = r; vcol[i] = (cb ^ ((r & 7) << 4)) >> 1;
  }
  const unsigned short* kbase = qkv + 2048 + h * HD;
  const unsigned short* vbase = vt + (size_t)h * HD * T_LEN;

#define STAGE_KV(BUF, S0)                                                              \
  do {                                                                                 \
    _Pragma("unroll")                                                                  \
    for (int i = 0; i < 4; ++i) {                                                      \
      GLDS16(kbase + (size_t)((S0) + krow[i]) * QKV_LD + kcol[i],                      \
             Ks[BUF] + i * 2048 + wave * 512);                                         \
      GLDS16(vbase + (size_t)vrow[i] * T_LEN + (S0) + vcol[i],                         \
             Vs[BUF] + i * 2048 + wave * 512);                                         \
    }                                                                                  \
  } while (0)

  STAGE_KV(0, 0);
  __syncthreads();

  const int NT = T_LEN / 64;
  int cur = 0;
  for (int t = 0; t < NT; ++t) {
    if (t + 1 < NT) STAGE_KV(cur ^ 1, (t + 1) * 64);

    const unsigned short* ks = Ks[cur];
    const unsigned short* vs = Vs[cur];

    // S^T = K Q^T : lane (l15,l16) holds S[kv = c*16 + l16*4 + j][q = l15]
    f32x4 st[4] = {};
#pragma unroll
    for (int c = 0; c < 4; ++c) {
#pragma unroll
      for (int kk = 0; kk < 4; ++kk) {
        int row = c * 16 + l15;
        int cb = kk * 64 + l16 * 16;
        short8 kf = *(const short8*)((const char*)ks + row * 256 + (cb ^ ((row & 7) << 4)));
        st[c] = mfma16(kf, qf[kk], st[c]);
      }
    }

    // online softmax, lane-local for q-row l15
    float ma = max3f(st[0][0], st[0][1], st[0][2]);
    float mb = max3f(st[0][3], st[1][0], st[1][1]);
    float mc = max3f(st[1][2], st[1][3], st[2][0]);
    float md = max3f(st[2][1], st[2][2], st[2][3]);
    float me = max3f(st[3][0], st[3][1], st[3][2]);
    float pmax = fmaxf(max3f(ma, mb, mc), max3f(md, me, st[3][3])) * SCL;
    pmax = fmaxf(pmax, __shfl_xor(pmax, 16));
    pmax = fmaxf(pmax, __shfl_xor(pmax, 32));

    if (!__all(pmax - m_r <= 8.0f)) {
      float nm = fmaxf(m_r, pmax);
      float corr = __builtin_amdgcn_exp2f(m_r - nm);
      m_r = nm;
      l_r *= corr;
      float cj[4];
#pragma unroll
      for (int j = 0; j < 4; ++j) cj[j] = __shfl(corr, l16 * 4 + j);
#pragma unroll
      for (int d = 0; d < 8; ++d)
#pragma unroll
        for (int j = 0; j < 4; ++j) acc_o[d][j] *= cj[j];
    }

    float p[4][4];
#pragma unroll
    for (int c = 0; c < 4; ++c)
#pragma unroll
      for (int j = 0; j < 4; ++j)
        p[c][j] = __builtin_amdgcn_exp2f(st[c][j] * SCL - m_r);
    float s01 = (p[0][0] + p[0][1]) + (p[0][2] + p[0][3]);
    float s23 = (p[1][0] + p[1][1]) + (p[1][2] + p[1][3]);
    float s45 = (p[2][0] + p[2][1]) + (p[2][2] + p[2][3]);
    float s67 = (p[3][0] + p[3][1]) + (p[3][2] + p[3][3]);
    float tsum = (s01 + s23) + (s45 + s67);
    tsum += __shfl_xor(tsum, 16);
    tsum += __shfl_xor(tsum, 32);
    l_r += tsum;

    char* pbase = (char*)Ps + wave * 2048;
#pragma unroll
    for (int c = 0; c < 4; ++c) {
      uint2v w;
      w.x = (unsigned)f2bf(p[c][0]) | ((unsigned)f2bf(p[c][1]) << 16);
      w.y = (unsigned)f2bf(p[c][2]) | ((unsigned)f2bf(p[c][3]) << 16);
      int off = l15 * 128 + c * 32 + l16 * 8;
      *(uint2v*)(pbase + (off ^ ((l15 & 7) << 4))) = w;
    }

#pragma unroll
    for (int kk = 0; kk < 2; ++kk) {
      int cb = kk * 64 + l16 * 16;
      short8 pa = *(const short8*)(pbase + l15 * 128 + (cb ^ ((l15 & 7) << 4)));
#pragma unroll
      for (int d = 0; d < 8; ++d) {
        int row = d * 16 + l15;
        short8 vb = *(const short8*)((const char*)vs + row * 128 + (cb ^ ((row & 7) << 4)));
        acc_o[d] = mfma16(pa, vb, acc_o[d]);
      }
    }

    __syncthreads();
    cur ^= 1;
  }
#undef STAGE_KV

  float lq[4];
#pragma unroll
  for (int j = 0; j < 4; ++j) lq[j] = 1.0f / __shfl(l_r, l16 * 4 + j);
#pragma unroll
  for (int d = 0; d < 8; ++d)
#pragma unroll
    for (int j = 0; j < 4; ++j) {
      int row = q0 + l16 * 4 + j;
      int col = h * HD + d * 16 + l15;
      ctx[(size_t)row * DIM + col] = f2bf(acc_o[d][j] * lq[j]);
    }
}

// ---------------------------------------------------------------- launcher
extern "C" void kernel_launch(void* const* d_in, const int* in_sizes, int n_in,
                              void* d_out, int out_size, void* d_ws, size_t ws_size,
                              hipStream_t stream) {
  const float* x = (const float*)d_in[0];
  const float* w_in = (const float*)d_in[1];
  const float* w_out = (const float*)d_in[2];

  char* ws = (char*)d_ws;
  unsigned short* xbf  = (unsigned short*)(ws + 0);          //  8 MB
  unsigned short* wibf = (unsigned short*)(ws + 8388608);    // 24 MB
  unsigned short* wobf = (unsigned short*)(ws + 33554432);   //  8 MB
  unsigned short* qkv  = (unsigned short*)(ws + 41943040);   // 24 MB (V third unused)
  unsigned short* ctx  = (unsigned short*)(ws + 67108864);   //  8 MB
  unsigned short* vt   = (unsigned short*)(ws + 75497472);   //  8 MB  (end: 80 MB)

  // fused fp32->bf16 casts (x, w_in, w_out) in one launch
  cast3_f32_bf16<<<2048, 256, 0, stream>>>(
      x, xbf, (T_LEN * DIM) / 4,
      w_in, wibf, (3 * DIM * DIM) / 4,
      w_out, wobf, (DIM * DIM) / 4);

  // qkv = x @ w_in^T; V third written TRANSPOSED directly into vt
  gemm_bt_128<2><<<dim3(48, 16), 256, 0, stream>>>(
      xbf, wibf, (void*)qkv, vt, T_LEN, 3 * DIM, DIM);
  // attention -> ctx [2048 x 2048] bf16
  attn_fwd<<<dim3(32, 16), 256, 0, stream>>>(qkv, vt, ctx);
  // out = ctx @ w_out^T  (fp32)
  gemm_bt_128<0><<<dim3(16, 16), 256, 0, stream>>>(
      ctx, wobf, d_out, nullptr, T_LEN, DIM, DIM);
}